// Round 7
// baseline (87.780 us; speedup 1.0000x reference)
//
#include <hip/hip_runtime.h>

// Persistence-image kernel, MI355X — R7 (= R6 resubmitted; container infra
// failure last round, kernel never ran): scalar-pipe corner data, LDS-free.
// S=128, I=32 intervals, C=32 corners, R=30 -> G=900.
// img[s,g] = sum_i w_i^2 * exp(-200 * max(min_c |g-b_ic|^2, min_c |g-d_ic|^2))
// |g-p|^2 = (r_c + qx_c*gx + qy_c*gy) + |g|^2, qx=-2px, qy=-2py, r=|p|^2.
//
// R1-R5 finding: the inner loop was LDS-broadcast-bound: 96 ds_read_b128 per
// wave x 12cyc x 32 waves/CU = 36.9K cyc/CU (~15.4us), independent of VALU
// cuts (R5 -23% VALU = same time) and of occupancy. Corner data is
// BLOCK-UNIFORM -> belongs on the scalar pipe, not LDS.
// R6/R7: prep transforms corners into ws as per-(s,i) packs [qxB32|qyB32|rB32|
// qxD32|qyD32|rD32]; pimg reads them at block-uniform addresses from
// const __restrict__ -> s_load into SGPRs (1 SGPR operand per VALU op is
// legal). pimg has NO LDS and NO barriers. Corner pairs use
// fminf(fminf(m,a),b) -> v_min3_f32 fusion: 8 VALU ops/corner.
// prep (128 blocks x 256 thr) owns transform + bbox + w2 + output zeroing.
// Register discipline (R2-R4 lesson): mb[4]/md[4]/acc[4] const-indexed,
// live set ~24 floats, (128,8) bounds -> 64-VGPR envelope that R1/R5 proved.
// ws footprint: 8192 + 128*32*192 floats ~= 3.1 MB << workspace.

#define RES 30
#define GPTS 900
#define NS 128
#define NI 32
#define INV29 (1.0f / 29.0f)
#define HDR_STRIDE 64                 // per-sample header: box[4] + w2[32]
#define CORN_BASE (NS * HDR_STRIDE)   // 8192 floats
#define I_STRIDE 192                  // per-(s,i) corner pack: 6*32 floats

__device__ __forceinline__ void store_corner(
    float* __restrict__ ws, int s, int cg, float px, float py, float dx, float dy)
{
    const int i = cg >> 5, c = cg & 31;
    float* b = ws + CORN_BASE + (size_t)(s * NI + i) * I_STRIDE + c;
    b[0]   = -2.f * px; b[32]  = -2.f * py; b[64]  = fmaf(px, px, py * py);
    b[96]  = -2.f * dx; b[128] = -2.f * dy; b[160] = fmaf(dx, dx, dy * dy);
}

__global__ __launch_bounds__(256) void prep_kernel(
    const float* __restrict__ births, const float* __restrict__ deaths,
    float* __restrict__ out, float* __restrict__ ws)
{
    const int s = blockIdx.x, tid = threadIdx.x;
    __shared__ float wc[1024];
    __shared__ float red[4][4];

    const float4* b4 = (const float4*)(births + (size_t)s * 2048);
    const float4* d4 = (const float4*)(deaths + (size_t)s * 2048);
    const float4 f0 = b4[tid], f1 = b4[tid + 256];
    const float4 g0 = d4[tid], g1 = d4[tid + 256];

    // bbox partials over the 4 float4s (8 points)
    float mnx = fminf(fminf(f0.x, f0.z), fminf(f1.x, f1.z));
    float mxx = fmaxf(fmaxf(f0.x, f0.z), fmaxf(f1.x, f1.z));
    float mny = fminf(fminf(f0.y, f0.w), fminf(f1.y, f1.w));
    float mxy = fmaxf(fmaxf(f0.y, f0.w), fmaxf(f1.y, f1.w));
    mnx = fminf(mnx, fminf(fminf(g0.x, g0.z), fminf(g1.x, g1.z)));
    mxx = fmaxf(mxx, fmaxf(fmaxf(g0.x, g0.z), fmaxf(g1.x, g1.z)));
    mny = fminf(mny, fminf(fminf(g0.y, g0.w), fminf(g1.y, g1.w)));
    mxy = fmaxf(mxy, fmaxf(fmaxf(g0.y, g0.w), fmaxf(g1.y, g1.w)));

    // per-corner weights (corner cg = 2*float4_idx + {0,1})
    wc[2 * tid]           = fmaxf(fabsf(g0.x - f0.x), fabsf(g0.y - f0.y));
    wc[2 * tid + 1]       = fmaxf(fabsf(g0.z - f0.z), fabsf(g0.w - f0.w));
    wc[512 + 2 * tid]     = fmaxf(fabsf(g1.x - f1.x), fabsf(g1.y - f1.y));
    wc[512 + 2 * tid + 1] = fmaxf(fabsf(g1.z - f1.z), fabsf(g1.w - f1.w));

    // transformed corner packs
    store_corner(ws, s, 2 * tid,           f0.x, f0.y, g0.x, g0.y);
    store_corner(ws, s, 2 * tid + 1,       f0.z, f0.w, g0.z, g0.w);
    store_corner(ws, s, 512 + 2 * tid,     f1.x, f1.y, g1.x, g1.y);
    store_corner(ws, s, 512 + 2 * tid + 1, f1.z, f1.w, g1.z, g1.w);

    #pragma unroll
    for (int off = 32; off > 0; off >>= 1) {
        mnx = fminf(mnx, __shfl_down(mnx, off));
        mny = fminf(mny, __shfl_down(mny, off));
        mxx = fmaxf(mxx, __shfl_down(mxx, off));
        mxy = fmaxf(mxy, __shfl_down(mxy, off));
    }
    const int wave = tid >> 6, lane = tid & 63;
    if (lane == 0) { red[wave][0] = mnx; red[wave][1] = mny; red[wave][2] = mxx; red[wave][3] = mxy; }
    __syncthreads();

    float* hdr = ws + (size_t)s * HDR_STRIDE;
    if (tid == 0) {
        const float a = fminf(fminf(red[0][0], red[1][0]), fminf(red[2][0], red[3][0]));
        const float b = fminf(fminf(red[0][1], red[1][1]), fminf(red[2][1], red[3][1]));
        const float c = fmaxf(fmaxf(red[0][2], red[1][2]), fmaxf(red[2][2], red[3][2]));
        const float d = fmaxf(fmaxf(red[0][3], red[1][3]), fmaxf(red[2][3], red[3][3]));
        const float mgx = 0.1f * (c - a), mgy = 0.1f * (d - b);
        hdr[0] = a - mgx; hdr[1] = b - mgy; hdr[2] = c + mgx; hdr[3] = d + mgy;
    }
    if (tid < NI) {  // deterministic serial sum of 32 per-corner weights
        float ssum = 0.f;
        #pragma unroll
        for (int k = 0; k < 32; ++k) ssum += wc[tid * 32 + k];
        const float w = ssum * (1.0f / 32.0f);
        hdr[4 + tid] = w * w;
    }
    // zero this sample's output slice (kernel-node zeroing: graph-replay-safe)
    #pragma unroll
    for (int k = 0; k < 4; ++k) {
        const int g = tid + 256 * k;
        if (g < GPTS) out[(size_t)s * GPTS + g] = 0.f;
    }
}

// per float4 (4 corners): p-setup 4x fma, then per row 4 fma + 2 min3.
#define QSTEP(M, cbp) \
    { \
        const float4 X  = ((const float4*)((cbp)))[q]; \
        const float4 Y  = ((const float4*)((cbp) + 32))[q]; \
        const float4 Rr = ((const float4*)((cbp) + 64))[q]; \
        const float p0 = fmaf(X.x, gx, Rr.x); \
        const float p1 = fmaf(X.y, gx, Rr.y); \
        const float p2 = fmaf(X.z, gx, Rr.z); \
        const float p3 = fmaf(X.w, gx, Rr.w); \
        _Pragma("unroll") \
        for (int j = 0; j < 4; ++j) { \
            M[j] = fminf(fminf(M[j], fmaf(Y.x, gy[j], p0)), fmaf(Y.y, gy[j], p1)); \
            M[j] = fminf(fminf(M[j], fmaf(Y.z, gy[j], p2)), fmaf(Y.w, gy[j], p3)); \
        } \
    }

__global__ __launch_bounds__(128, 8) void pimg_kernel(
    float* __restrict__ out, const float* __restrict__ ws)
{
    const int bid = blockIdx.x;
    const int s   = bid >> 5;
    const int i0  = ((bid >> 1) & 15) * 2;
    const int gh  = bid & 1;
    const int tid = threadIdx.x;

    // header (block-uniform -> scalar loads)
    const float* hdr = ws + (size_t)s * HDR_STRIDE;
    const float lox = hdr[0], loy = hdr[1];
    const float sx  = (hdr[2] - lox) * INV29;
    const float sy  = (hdr[3] - loy) * INV29;
    const float w2a = hdr[4 + i0];
    const float w2b = hdr[4 + i0 + 1];

    // thread -> (column c of this gh-half, row-quad rq); masked at stores
    const int c   = tid >> 3;          // 0..15 (15 masked)
    const int rq  = tid & 7;           // 0..7
    const int ix  = gh * 15 + c;
    const int iy0 = rq * 4;            // rows iy0..iy0+3 (30,31 masked)

    const float gx = fmaf((float)ix, sx, lox);
    float gy[4], acc[4];
    #pragma unroll
    for (int j = 0; j < 4; ++j) {
        gy[j]  = fmaf((float)(iy0 + j), sy, loy);
        acc[j] = 0.f;
    }

    #pragma unroll 1
    for (int il = 0; il < 2; ++il) {
        // block-uniform corner pack base -> s_load territory
        const float* cb = ws + CORN_BASE + (size_t)(s * NI + i0 + il) * I_STRIDE;

        float mb[4], md[4];
        #pragma unroll
        for (int j = 0; j < 4; ++j) { mb[j] = 3e38f; md[j] = 3e38f; }

        #pragma unroll
        for (int q = 0; q < 8; ++q) QSTEP(mb, cb)        // births
        #pragma unroll
        for (int q = 0; q < 8; ++q) QSTEP(md, cb + 96)   // deaths

        const float w2  = il ? w2b : w2a;
        const float gxs = gx * gx;
        #pragma unroll
        for (int j = 0; j < 4; ++j) {
            const float t = fmaxf(mb[j], md[j]) + fmaf(gy[j], gy[j], gxs);
            acc[j] = fmaf(w2, __expf(-200.0f * t), acc[j]);
        }
    }

    if (c < 15) {
        float* op = out + (size_t)s * GPTS + ix * RES + iy0;
        #pragma unroll
        for (int j = 0; j < 4; ++j) {
            if (iy0 + j < RES) atomicAdd(&op[j], acc[j]);
        }
    }
}

extern "C" void kernel_launch(void* const* d_in, const int* in_sizes, int n_in,
                              void* d_out, int out_size, void* d_ws, size_t ws_size,
                              hipStream_t stream) {
    const float* births = (const float*)d_in[0];
    const float* deaths = (const float*)d_in[1];
    float* out = (float*)d_out;
    float* ws  = (float*)d_ws;

    prep_kernel<<<NS, 256, 0, stream>>>(births, deaths, out, ws);
    pimg_kernel<<<NS * 32, 128, 0, stream>>>(out, ws);
}

// Round 8
// 75.874 us; speedup vs baseline: 1.1569x; 1.1569x over previous
//
#include <hip/hip_runtime.h>

// Persistence-image kernel, MI355X — R8: exact-R1 structure + min3 pairing
// + load-pipe split (births via LDS, deaths via uniform VMEM pack).
// S=128, I=32 intervals, C=32 corners, R=30 -> G=900.
// img[s,g] = sum_i w_i^2 * exp(-200 * max(min_c |g-b_ic|^2, min_c |g-d_ic|^2))
// |g-p|^2 = (r_c + qx_c*gx + qy_c*gy) + |g|^2, qx=-2px, qy=-2py, r=|p|^2.
//
// Round history: R1 (74us) is the fastest verified structure. Both
// column-sharing rewrites (R5 LDS, R7 scalar) cost +13.5us with identical
// totals -> the rewrite itself regresses, and LDS-vs-VMEM for uniform corner
// loads is rate-equivalent (R5==R7). So: keep R1's exact thread/block mapping,
// in-block bbox/w2, 64-VGPR envelope; change ONLY
//  (1) fminf pairing -> v_min3_f32: 12 -> 10 VALU/corner/pt (-17% inner VALU);
//  (2) deaths read from a prep-built SoA pack at block-uniform addresses
//      (48 loads on VMEM/scalar pipe) while births stay in LDS (48 ds_reads):
//      halves per-pipe load pressure vs R1's 96-on-LDS.
// prep (128 blocks x 256 thr) transforms deaths + zeroes out (graph-safe
// kernel node, replaces zero_out; bbox/w2 stay in-block as R1 proved).

#define RES 30
#define GPTS 900
#define NS 128
#define NI 32
#define D_STRIDE 96   // per-(s,i) deaths pack: qx[32] | qy[32] | r[32]

__global__ __launch_bounds__(256) void prep_kernel(
    const float* __restrict__ deaths, float* __restrict__ out,
    float* __restrict__ ws)
{
    const int s = blockIdx.x, tid = threadIdx.x;
    // thread -> 4 consecutive corners of sample s (1024 corners total)
    const float4* d4 = (const float4*)(deaths + (size_t)s * 2048);
    const float4 d0 = d4[2 * tid];      // corners 4t, 4t+1 (x0,y0,x1,y1)
    const float4 d1 = d4[2 * tid + 1];  // corners 4t+2, 4t+3

    const int i = tid >> 3;             // interval 0..31
    const int c = 4 * (tid & 7);        // corner-in-interval 0,4,..,28
    float* p = ws + (size_t)(s * NI + i) * D_STRIDE + c;
    p[0]      = -2.f * d0.x; p[1]      = -2.f * d0.z;
    p[2]      = -2.f * d1.x; p[3]      = -2.f * d1.z;
    p[32]     = -2.f * d0.y; p[33]     = -2.f * d0.w;
    p[34]     = -2.f * d1.y; p[35]     = -2.f * d1.w;
    p[64]     = fmaf(d0.x, d0.x, d0.y * d0.y);
    p[65]     = fmaf(d0.z, d0.z, d0.w * d0.w);
    p[66]     = fmaf(d1.x, d1.x, d1.y * d1.y);
    p[67]     = fmaf(d1.z, d1.z, d1.w * d1.w);

    // zero this sample's output slice (900 floats = 225 float4, 16B-aligned)
    if (tid < 225) ((float4*)(out + (size_t)s * GPTS))[tid] =
        make_float4(0.f, 0.f, 0.f, 0.f);
}

__global__ __launch_bounds__(128, 8) void pimg_kernel(
    const float* __restrict__ births, const float* __restrict__ deaths,
    float* __restrict__ out, const float* __restrict__ ws)
{
    const int bid = blockIdx.x;
    const int s   = bid >> 5;
    const int i0  = ((bid >> 1) & 15) * 2;
    const int gh  = bid & 1;
    const int tid = threadIdx.x;

    __shared__ __align__(16) float Bqx[64], Bqy[64], Br[64];
    __shared__ float wred[64];
    __shared__ float red[2][4];
    __shared__ float box[4];
    __shared__ float w2s[2];

    // ---- births corner transform -> LDS; deaths only for wred (threads 0..63)
    if (tid < 64) {
        const size_t base = (size_t)s * 1024 + (size_t)i0 * 32 + tid;
        const float2 pb = ((const float2*)births)[base];
        Bqx[tid] = -2.f * pb.x; Bqy[tid] = -2.f * pb.y; Br[tid] = pb.x * pb.x + pb.y * pb.y;
        const float2 pd = ((const float2*)deaths)[base];
        wred[tid] = fmaxf(fabsf(pd.x - pb.x), fabsf(pd.y - pb.y));
    }

    // ---- redundant per-block bbox over all 2048 points of sample s (as R1)
    {
        const float4* b4 = (const float4*)(births + (size_t)s * 2048);
        const float4* d4 = (const float4*)(deaths + (size_t)s * 2048);
        float mnx = 3e38f, mny = 3e38f, mxx = -3e38f, mxy = -3e38f;
        #pragma unroll
        for (int k = 0; k < 4; ++k) {
            float4 f = b4[tid + 128 * k];
            mnx = fminf(mnx, fminf(f.x, f.z)); mxx = fmaxf(mxx, fmaxf(f.x, f.z));
            mny = fminf(mny, fminf(f.y, f.w)); mxy = fmaxf(mxy, fmaxf(f.y, f.w));
            float4 g = d4[tid + 128 * k];
            mnx = fminf(mnx, fminf(g.x, g.z)); mxx = fmaxf(mxx, fmaxf(g.x, g.z));
            mny = fminf(mny, fminf(g.y, g.w)); mxy = fmaxf(mxy, fmaxf(g.y, g.w));
        }
        #pragma unroll
        for (int off = 32; off > 0; off >>= 1) {
            mnx = fminf(mnx, __shfl_down(mnx, off));
            mny = fminf(mny, __shfl_down(mny, off));
            mxx = fmaxf(mxx, __shfl_down(mxx, off));
            mxy = fmaxf(mxy, __shfl_down(mxy, off));
        }
        const int wave = tid >> 6, lane = tid & 63;
        if (lane == 0) { red[wave][0] = mnx; red[wave][1] = mny; red[wave][2] = mxx; red[wave][3] = mxy; }
    }
    __syncthreads();

    if (tid == 0) {
        const float a = fminf(red[0][0], red[1][0]);
        const float b = fminf(red[0][1], red[1][1]);
        const float c = fmaxf(red[0][2], red[1][2]);
        const float d = fmaxf(red[0][3], red[1][3]);
        const float mgx = 0.1f * (c - a), mgy = 0.1f * (d - b);
        box[0] = a - mgx; box[1] = b - mgy; box[2] = c + mgx; box[3] = d + mgy;
    }
    if (tid < 2) {  // deterministic serial sum of 32 per-corner weights
        float ssum = 0.f;
        #pragma unroll
        for (int k = 0; k < 32; ++k) ssum += wred[tid * 32 + k];
        const float w = ssum * (1.0f / 32.0f);
        w2s[tid] = w * w;
    }
    __syncthreads();

    const float lox = box[0], loy = box[1];
    const float sx  = (box[2] - lox) * (1.0f / 29.0f);
    const float sy  = (box[3] - loy) * (1.0f / 29.0f);

    // j-interleaved g assignment: g = tid + 128*(2j+gh) -> balanced halves
    float gx[4], gy[4], acc[4];
    #pragma unroll
    for (int j = 0; j < 4; ++j) {
        const int g  = tid + 128 * (2 * j + gh);
        const int ix = g / RES, iy = g - ix * RES;
        gx[j]  = lox + (float)ix * sx;
        gy[j]  = loy + (float)iy * sy;
        acc[j] = 0.f;
    }

    const float4* Bqx4 = (const float4*)Bqx;
    const float4* Bqy4 = (const float4*)Bqy;
    const float4* Br4  = (const float4*)Br;

    #pragma unroll 1
    for (int il = 0; il < 2; ++il) {
        // deaths pack, block-uniform base -> scalar/VMEM pipe
        const float* dp = ws + (size_t)(s * NI + i0 + il) * D_STRIDE;
        const float4* DX = (const float4*)dp;
        const float4* DY = (const float4*)(dp + 32);
        const float4* DR = (const float4*)(dp + 64);

        float mb[4], md[4];
        #pragma unroll
        for (int j = 0; j < 4; ++j) { mb[j] = 3e38f; md[j] = 3e38f; }

        #pragma unroll
        for (int q = 0; q < 8; ++q) {            // births from LDS
            const float4 X  = Bqx4[il * 8 + q];
            const float4 Y  = Bqy4[il * 8 + q];
            const float4 Rr = Br4[il * 8 + q];
            #pragma unroll
            for (int j = 0; j < 4; ++j) {
                float a0 = fmaf(X.x, gx[j], Rr.x); a0 = fmaf(Y.x, gy[j], a0);
                float a1 = fmaf(X.y, gx[j], Rr.y); a1 = fmaf(Y.y, gy[j], a1);
                mb[j] = fminf(fminf(mb[j], a0), a1);   // v_min3_f32
                float a2 = fmaf(X.z, gx[j], Rr.z); a2 = fmaf(Y.z, gy[j], a2);
                float a3 = fmaf(X.w, gx[j], Rr.w); a3 = fmaf(Y.w, gy[j], a3);
                mb[j] = fminf(fminf(mb[j], a2), a3);   // v_min3_f32
            }
        }
        #pragma unroll
        for (int q = 0; q < 8; ++q) {            // deaths from uniform pack
            const float4 X  = DX[q];
            const float4 Y  = DY[q];
            const float4 Rr = DR[q];
            #pragma unroll
            for (int j = 0; j < 4; ++j) {
                float a0 = fmaf(X.x, gx[j], Rr.x); a0 = fmaf(Y.x, gy[j], a0);
                float a1 = fmaf(X.y, gx[j], Rr.y); a1 = fmaf(Y.y, gy[j], a1);
                md[j] = fminf(fminf(md[j], a0), a1);   // v_min3_f32
                float a2 = fmaf(X.z, gx[j], Rr.z); a2 = fmaf(Y.z, gy[j], a2);
                float a3 = fmaf(X.w, gx[j], Rr.w); a3 = fmaf(Y.w, gy[j], a3);
                md[j] = fminf(fminf(md[j], a2), a3);   // v_min3_f32
            }
        }

        const float w2 = w2s[il];
        #pragma unroll
        for (int j = 0; j < 4; ++j) {
            const float gg = gx[j] * gx[j] + gy[j] * gy[j];
            const float t  = fmaxf(mb[j], md[j]) + gg;
            acc[j] = fmaf(w2, __expf(-200.0f * t), acc[j]);
        }
    }

    #pragma unroll
    for (int j = 0; j < 4; ++j) {
        const int g = tid + 128 * (2 * j + gh);
        if (g < GPTS) atomicAdd(&out[(size_t)s * GPTS + g], acc[j]);
    }
}

extern "C" void kernel_launch(void* const* d_in, const int* in_sizes, int n_in,
                              void* d_out, int out_size, void* d_ws, size_t ws_size,
                              hipStream_t stream) {
    const float* births = (const float*)d_in[0];
    const float* deaths = (const float*)d_in[1];
    float* out = (float*)d_out;
    float* ws  = (float*)d_ws;

    prep_kernel<<<NS, 256, 0, stream>>>(deaths, out, ws);
    pimg_kernel<<<NS * 32, 128, 0, stream>>>(births, deaths, out, ws);
}

// Round 9
// 73.351 us; speedup vs baseline: 1.1967x; 1.0344x over previous
//
#include <hip/hip_runtime.h>

// Persistence-image kernel, MI355X — R9: R8 inner loop verbatim + preamble
// fully hoisted to prep (bbox, w^2, deaths pack, output zeroing).
// S=128, I=32 intervals, C=32 corners, R=30 -> G=900.
// img[s,g] = sum_i w_i^2 * exp(-200 * max(min_c |g-b_ic|^2, min_c |g-d_ic|^2))
// |g-p|^2 = (r_c + qx_c*gx + qy_c*gy) + |g|^2, qx=-2px, qy=-2py, r=|p|^2.
//
// Evidence through R8: R1 structure = 74-76us total; inner-loop VALU cuts
// (min3, column-sharing) and load-pipe moves (LDS vs uniform VMEM) are all
// invisible; column REWRITES regress +12us. Only untested lever inside the
// R1 envelope: the per-block preamble (8x float4 global re-reads = 64MB
// grid-wide, 24-shfl tree, 32-iter serial w-sum on 2 lanes, 2 barriers),
// paid by all 4096 blocks. R9 removes exactly that, nothing else:
//  - prep (128 blocks x 256 thr): bbox+w2 -> ws header, deaths SoA pack
//    (R8 layout), zeroes out. One kernel node, graph-replay-safe.
//  - pimg: births->LDS transform (tid<64) + ONE barrier, box/w2 via
//    block-uniform scalar loads, then R8's exact inner loop (min3 pairing,
//    births-LDS + deaths-uniform-VMEM split), same atomics.
// Register discipline: pimg only LOSES code vs R8 -> same 64-VGPR envelope.

#define RES 30
#define GPTS 900
#define NS 128
#define NI 32
#define HDR_STRIDE 64   // per-sample: box[4] + pad[28] + w2[32]
#define CORN_BASE (NS * HDR_STRIDE)
#define D_STRIDE 96     // per-(s,i) deaths pack: qx[32] | qy[32] | r[32]

__global__ __launch_bounds__(256) void prep_kernel(
    const float* __restrict__ births, const float* __restrict__ deaths,
    float* __restrict__ out, float* __restrict__ ws)
{
    const int s = blockIdx.x, tid = threadIdx.x;
    __shared__ float wc[1024];
    __shared__ float red[4][4];

    const float4* b4 = (const float4*)(births + (size_t)s * 2048);
    const float4* d4 = (const float4*)(deaths + (size_t)s * 2048);
    const float4 b0 = b4[2 * tid], b1 = b4[2 * tid + 1];
    const float4 d0 = d4[2 * tid], d1 = d4[2 * tid + 1];

    // ---- deaths SoA pack (R8 layout): corners 4t..4t+3
    {
        const int i = tid >> 3;             // interval 0..31
        const int c = 4 * (tid & 7);        // corner base 0,4,..,28
        float* p = ws + CORN_BASE + (size_t)(s * NI + i) * D_STRIDE + c;
        p[0]  = -2.f * d0.x; p[1]  = -2.f * d0.z;
        p[2]  = -2.f * d1.x; p[3]  = -2.f * d1.z;
        p[32] = -2.f * d0.y; p[33] = -2.f * d0.w;
        p[34] = -2.f * d1.y; p[35] = -2.f * d1.w;
        p[64] = fmaf(d0.x, d0.x, d0.y * d0.y);
        p[65] = fmaf(d0.z, d0.z, d0.w * d0.w);
        p[66] = fmaf(d1.x, d1.x, d1.y * d1.y);
        p[67] = fmaf(d1.z, d1.z, d1.w * d1.w);
    }

    // ---- per-corner weights (corner 4t..4t+3)
    wc[4 * tid + 0] = fmaxf(fabsf(d0.x - b0.x), fabsf(d0.y - b0.y));
    wc[4 * tid + 1] = fmaxf(fabsf(d0.z - b0.z), fabsf(d0.w - b0.w));
    wc[4 * tid + 2] = fmaxf(fabsf(d1.x - b1.x), fabsf(d1.y - b1.y));
    wc[4 * tid + 3] = fmaxf(fabsf(d1.z - b1.z), fabsf(d1.w - b1.w));

    // ---- bbox over all 2048 points
    float mnx = fminf(fminf(b0.x, b0.z), fminf(b1.x, b1.z));
    float mxx = fmaxf(fmaxf(b0.x, b0.z), fmaxf(b1.x, b1.z));
    float mny = fminf(fminf(b0.y, b0.w), fminf(b1.y, b1.w));
    float mxy = fmaxf(fmaxf(b0.y, b0.w), fmaxf(b1.y, b1.w));
    mnx = fminf(mnx, fminf(fminf(d0.x, d0.z), fminf(d1.x, d1.z)));
    mxx = fmaxf(mxx, fmaxf(fmaxf(d0.x, d0.z), fmaxf(d1.x, d1.z)));
    mny = fminf(mny, fminf(fminf(d0.y, d0.w), fminf(d1.y, d1.w)));
    mxy = fmaxf(mxy, fmaxf(fmaxf(d0.y, d0.w), fmaxf(d1.y, d1.w)));
    #pragma unroll
    for (int off = 32; off > 0; off >>= 1) {
        mnx = fminf(mnx, __shfl_down(mnx, off));
        mny = fminf(mny, __shfl_down(mny, off));
        mxx = fmaxf(mxx, __shfl_down(mxx, off));
        mxy = fmaxf(mxy, __shfl_down(mxy, off));
    }
    const int wave = tid >> 6, lane = tid & 63;
    if (lane == 0) { red[wave][0] = mnx; red[wave][1] = mny; red[wave][2] = mxx; red[wave][3] = mxy; }
    __syncthreads();

    float* hdr = ws + (size_t)s * HDR_STRIDE;
    if (tid == 0) {
        const float a = fminf(fminf(red[0][0], red[1][0]), fminf(red[2][0], red[3][0]));
        const float b = fminf(fminf(red[0][1], red[1][1]), fminf(red[2][1], red[3][1]));
        const float c = fmaxf(fmaxf(red[0][2], red[1][2]), fmaxf(red[2][2], red[3][2]));
        const float d = fmaxf(fmaxf(red[0][3], red[1][3]), fmaxf(red[2][3], red[3][3]));
        const float mgx = 0.1f * (c - a), mgy = 0.1f * (d - b);
        hdr[0] = a - mgx; hdr[1] = b - mgy; hdr[2] = c + mgx; hdr[3] = d + mgy;
    }
    if (tid < NI) {  // deterministic serial sum, same order as R1 (absmax-proven)
        float ssum = 0.f;
        #pragma unroll
        for (int k = 0; k < 32; ++k) ssum += wc[tid * 32 + k];
        const float w = ssum * (1.0f / 32.0f);
        hdr[32 + tid] = w * w;
    }
    // zero this sample's output slice (900 floats = 225 float4)
    if (tid < 225) ((float4*)(out + (size_t)s * GPTS))[tid] =
        make_float4(0.f, 0.f, 0.f, 0.f);
}

__global__ __launch_bounds__(128, 8) void pimg_kernel(
    const float* __restrict__ births, float* __restrict__ out,
    const float* __restrict__ ws)
{
    const int bid = blockIdx.x;
    const int s   = bid >> 5;
    const int i0  = ((bid >> 1) & 15) * 2;
    const int gh  = bid & 1;
    const int tid = threadIdx.x;

    __shared__ __align__(16) float Bqx[64], Bqy[64], Br[64];

    // births corner transform -> LDS (threads 0..63); single barrier below
    if (tid < 64) {
        const size_t base = (size_t)s * 1024 + (size_t)i0 * 32 + tid;
        const float2 pb = ((const float2*)births)[base];
        Bqx[tid] = -2.f * pb.x; Bqy[tid] = -2.f * pb.y; Br[tid] = pb.x * pb.x + pb.y * pb.y;
    }

    // box + weights: block-uniform -> scalar loads, overlap the LDS writes
    const float* hdr = ws + (size_t)s * HDR_STRIDE;
    const float lox = hdr[0], loy = hdr[1];
    const float sx  = (hdr[2] - lox) * (1.0f / 29.0f);
    const float sy  = (hdr[3] - loy) * (1.0f / 29.0f);
    const float w2a = hdr[32 + i0];
    const float w2b = hdr[32 + i0 + 1];

    __syncthreads();

    // j-interleaved g assignment: g = tid + 128*(2j+gh) (R1 mapping)
    float gx[4], gy[4], acc[4];
    #pragma unroll
    for (int j = 0; j < 4; ++j) {
        const int g  = tid + 128 * (2 * j + gh);
        const int ix = g / RES, iy = g - ix * RES;
        gx[j]  = lox + (float)ix * sx;
        gy[j]  = loy + (float)iy * sy;
        acc[j] = 0.f;
    }

    const float4* Bqx4 = (const float4*)Bqx;
    const float4* Bqy4 = (const float4*)Bqy;
    const float4* Br4  = (const float4*)Br;

    #pragma unroll 1
    for (int il = 0; il < 2; ++il) {
        // deaths pack, block-uniform base -> scalar/VMEM pipe
        const float* dp = ws + CORN_BASE + (size_t)(s * NI + i0 + il) * D_STRIDE;
        const float4* DX = (const float4*)dp;
        const float4* DY = (const float4*)(dp + 32);
        const float4* DR = (const float4*)(dp + 64);

        float mb[4], md[4];
        #pragma unroll
        for (int j = 0; j < 4; ++j) { mb[j] = 3e38f; md[j] = 3e38f; }

        #pragma unroll
        for (int q = 0; q < 8; ++q) {            // births from LDS
            const float4 X  = Bqx4[il * 8 + q];
            const float4 Y  = Bqy4[il * 8 + q];
            const float4 Rr = Br4[il * 8 + q];
            #pragma unroll
            for (int j = 0; j < 4; ++j) {
                float a0 = fmaf(X.x, gx[j], Rr.x); a0 = fmaf(Y.x, gy[j], a0);
                float a1 = fmaf(X.y, gx[j], Rr.y); a1 = fmaf(Y.y, gy[j], a1);
                mb[j] = fminf(fminf(mb[j], a0), a1);   // v_min3_f32
                float a2 = fmaf(X.z, gx[j], Rr.z); a2 = fmaf(Y.z, gy[j], a2);
                float a3 = fmaf(X.w, gx[j], Rr.w); a3 = fmaf(Y.w, gy[j], a3);
                mb[j] = fminf(fminf(mb[j], a2), a3);   // v_min3_f32
            }
        }
        #pragma unroll
        for (int q = 0; q < 8; ++q) {            // deaths from uniform pack
            const float4 X  = DX[q];
            const float4 Y  = DY[q];
            const float4 Rr = DR[q];
            #pragma unroll
            for (int j = 0; j < 4; ++j) {
                float a0 = fmaf(X.x, gx[j], Rr.x); a0 = fmaf(Y.x, gy[j], a0);
                float a1 = fmaf(X.y, gx[j], Rr.y); a1 = fmaf(Y.y, gy[j], a1);
                md[j] = fminf(fminf(md[j], a0), a1);   // v_min3_f32
                float a2 = fmaf(X.z, gx[j], Rr.z); a2 = fmaf(Y.z, gy[j], a2);
                float a3 = fmaf(X.w, gx[j], Rr.w); a3 = fmaf(Y.w, gy[j], a3);
                md[j] = fminf(fminf(md[j], a2), a3);   // v_min3_f32
            }
        }

        const float w2 = il ? w2b : w2a;
        #pragma unroll
        for (int j = 0; j < 4; ++j) {
            const float gg = gx[j] * gx[j] + gy[j] * gy[j];
            const float t  = fmaxf(mb[j], md[j]) + gg;
            acc[j] = fmaf(w2, __expf(-200.0f * t), acc[j]);
        }
    }

    #pragma unroll
    for (int j = 0; j < 4; ++j) {
        const int g = tid + 128 * (2 * j + gh);
        if (g < GPTS) atomicAdd(&out[(size_t)s * GPTS + g], acc[j]);
    }
}

extern "C" void kernel_launch(void* const* d_in, const int* in_sizes, int n_in,
                              void* d_out, int out_size, void* d_ws, size_t ws_size,
                              hipStream_t stream) {
    const float* births = (const float*)d_in[0];
    const float* deaths = (const float*)d_in[1];
    float* out = (float*)d_out;
    float* ws  = (float*)d_ws;

    prep_kernel<<<NS, 256, 0, stream>>>(births, deaths, out, ws);
    pimg_kernel<<<NS * 32, 128, 0, stream>>>(births, out, ws);
}